// Round 2
// baseline (84.329 us; speedup 1.0000x reference)
//
#include <hip/hip_runtime.h>

#define EMBED_DIM 256
#define MAX_SIZE 32

// One 64-lane wave per hyperedge. Lane l owns float4 at dims [4l, 4l+3].
__global__ void __launch_bounds__(256) hyperedge_mean_kernel(
    const float* __restrict__ emb,      // [N, 256]
    const int*   __restrict__ edges,    // [B, 32]
    const int*   __restrict__ lens,     // [B]
    float*       __restrict__ out,      // [B, 256]
    int B)
{
    const int gwave = (int)((blockIdx.x * blockDim.x + threadIdx.x) >> 6);
    const int lane  = threadIdx.x & 63;
    if (gwave >= B) return;

    int len = lens[gwave];
    if (len < 1) len = 1;
    if (len > MAX_SIZE) len = MAX_SIZE;
    const int* __restrict__ e = edges + (size_t)gwave * MAX_SIZE;

    float4 acc = make_float4(0.f, 0.f, 0.f, 0.f);

    int j = 0;
    // 2-deep manual unroll so two independent gathers are in flight.
    for (; j + 2 <= len; j += 2) {
        const int i0 = e[j];
        const int i1 = e[j + 1];
        const float4 v0 = reinterpret_cast<const float4*>(emb + (size_t)i0 * EMBED_DIM)[lane];
        const float4 v1 = reinterpret_cast<const float4*>(emb + (size_t)i1 * EMBED_DIM)[lane];
        acc.x += v0.x + v1.x;
        acc.y += v0.y + v1.y;
        acc.z += v0.z + v1.z;
        acc.w += v0.w + v1.w;
    }
    if (j < len) {
        const int i0 = e[j];
        const float4 v0 = reinterpret_cast<const float4*>(emb + (size_t)i0 * EMBED_DIM)[lane];
        acc.x += v0.x;
        acc.y += v0.y;
        acc.z += v0.z;
        acc.w += v0.w;
    }

    const float inv = 1.0f / (float)len;
    acc.x *= inv; acc.y *= inv; acc.z *= inv; acc.w *= inv;

    reinterpret_cast<float4*>(out + (size_t)gwave * EMBED_DIM)[lane] = acc;
}

extern "C" void kernel_launch(void* const* d_in, const int* in_sizes, int n_in,
                              void* d_out, int out_size, void* d_ws, size_t ws_size,
                              hipStream_t stream) {
    const float* emb   = (const float*)d_in[0];  // [100000, 256] fp32
    const int*   edges = (const int*)d_in[1];    // [32768, 32]  int
    const int*   lens  = (const int*)d_in[2];    // [32768]      int
    float*       out   = (float*)d_out;          // [32768, 256] fp32

    // B derived from the output size (unambiguous): out is [B, EMBED_DIM].
    const int B = out_size / EMBED_DIM;          // 32768 hyperedges
    const int waves_per_block = 4;               // 256 threads
    const int blocks = (B + waves_per_block - 1) / waves_per_block;

    hyperedge_mean_kernel<<<blocks, 256, 0, stream>>>(emb, edges, lens, out, B);
}